// Round 23
// baseline (1891.368 us; speedup 1.0000x reference)
//
#include <hip/hip_runtime.h>
#include <hip/hip_bf16.h>

typedef __attribute__((ext_vector_type(8))) short bf16x8;
typedef __attribute__((ext_vector_type(4))) float f32x4;
typedef __hip_bfloat16 bf16;

constexpr int DM   = 1024;
constexpr int NH   = 16;
constexpr int HD   = 64;
constexpr int FF   = 4096;
constexpr int NL   = 6;
constexpr int NB_  = 8;
constexpr int SEQL = 512;
constexpr int NTOK = NB_ * SEQL;   // 4096

// ---------------- async global->LDS (16B) ----------------
__device__ __forceinline__ void gl_lds16(const void* g, void* l) {
  __builtin_amdgcn_global_load_lds(
      (const __attribute__((address_space(1))) unsigned int*)g,
      (__attribute__((address_space(3))) unsigned int*)l, 16, 0, 0);
}

__device__ __forceinline__ float4 ld_bf16x4(const bf16* p) {
  union { uint2 u; bf16 h[4]; } t;
  t.u = *(const uint2*)p;
  return make_float4(__bfloat162float(t.h[0]), __bfloat162float(t.h[1]),
                     __bfloat162float(t.h[2]), __bfloat162float(t.h[3]));
}

// ---------------- weight transpose + f32->bf16 (vectorized, 64x64 tiles) ----
__global__ __launch_bounds__(256) void transpose_cvt(const float* __restrict__ src,
                                                     bf16* __restrict__ dst,
                                                     int R, int C) {
  __shared__ float tile[64][65];
  size_t mo = (size_t)blockIdx.z * R * C;
  src += mo; dst += mo;
  int c0 = blockIdx.x * 64, r0 = blockIdx.y * 64;
  int t = threadIdx.x;
  int cq = (t & 15) * 4;
  int rw = t >> 4;
  #pragma unroll
  for (int p = 0; p < 4; ++p) {
    int row = rw + p * 16;
    float4 v = *(const float4*)(src + (size_t)(r0 + row) * C + c0 + cq);
    tile[row][cq]     = v.x;
    tile[row][cq + 1] = v.y;
    tile[row][cq + 2] = v.z;
    tile[row][cq + 3] = v.w;
  }
  __syncthreads();
  int rq = (t & 15) * 4;
  int cw = t >> 4;
  #pragma unroll
  for (int p = 0; p < 4; ++p) {
    int cc = cw + p * 16;
    union { bf16 h[4]; unsigned long long u; } o;
    o.h[0] = __float2bfloat16(tile[rq][cc]);
    o.h[1] = __float2bfloat16(tile[rq + 1][cc]);
    o.h[2] = __float2bfloat16(tile[rq + 2][cc]);
    o.h[3] = __float2bfloat16(tile[rq + 3][cc]);
    *(unsigned long long*)(dst + (size_t)(c0 + cc) * R + r0 + rq) = o.u;
  }
}

__global__ __launch_bounds__(256) void cvt_bf16(const float* __restrict__ s,
                                                bf16* __restrict__ d) {
  size_t i = (size_t)blockIdx.x * 256 + threadIdx.x;
  float4 v = ((const float4*)s)[i];
  union { bf16 h[4]; uint2 u; } t;
  t.h[0] = __float2bfloat16(v.x); t.h[1] = __float2bfloat16(v.y);
  t.h[2] = __float2bfloat16(v.z); t.h[3] = __float2bfloat16(v.w);
  *(uint2*)(d + i * 4) = t.u;
}

// ---------------- embedding + positional encoding ----------------
__global__ __launch_bounds__(256) void embed_pe(const int* __restrict__ tok,
                                                const float* __restrict__ table,
                                                float* __restrict__ x) {
  int t = blockIdx.x;
  int s = t & (SEQL - 1);
  int tk = tok[t];
  int d = threadIdx.x * 4;
  float4 e = *(const float4*)(table + (size_t)tk * DM + d);
  float o[4] = {e.x, e.y, e.z, e.w};
  const float NEGC = -9.210340371976184f / 1024.0f;   // -ln(10000)/D
  #pragma unroll
  for (int i = 0; i < 4; ++i) {
    int dd = d + i;
    float div = __expf((float)(dd & ~1) * NEGC);
    float arg = (float)s * div;
    float pe = (dd & 1) ? cosf(arg) : sinf(arg);
    o[i] = o[i] * 32.0f + pe;       // sqrt(1024)=32
  }
  float4 ov = {o[0], o[1], o[2], o[3]};
  *(float4*)(x + (size_t)t * DM + d) = ov;
}

// ---------------- layernorm: one ROW per WAVE ----------
__device__ __forceinline__ void ln_wave(float4 v[4], const float* __restrict__ g,
                                        const float* __restrict__ bb,
                                        int row, int lane, bf16* ob, float* of, int outf32) {
  float s = 0.0f;
  #pragma unroll
  for (int i = 0; i < 4; ++i) s += v[i].x + v[i].y + v[i].z + v[i].w;
  #pragma unroll
  for (int o = 32; o; o >>= 1) s += __shfl_xor(s, o);
  float mean = s * (1.0f / DM);
  float s2 = 0.0f;
  #pragma unroll
  for (int i = 0; i < 4; ++i) {
    v[i].x -= mean; v[i].y -= mean; v[i].z -= mean; v[i].w -= mean;
    s2 += v[i].x*v[i].x + v[i].y*v[i].y + v[i].z*v[i].z + v[i].w*v[i].w;
  }
  #pragma unroll
  for (int o = 32; o; o >>= 1) s2 += __shfl_xor(s2, o);
  float rs = rsqrtf(s2 * (1.0f / DM) + 1e-5f);
  #pragma unroll
  for (int i = 0; i < 4; ++i) {
    int c = (lane + i * 64) * 4;
    float4 gg = *(const float4*)(g + c);
    float4 bv = *(const float4*)(bb + c);
    float y0 = v[i].x * rs * gg.x + bv.x;
    float y1 = v[i].y * rs * gg.y + bv.y;
    float y2 = v[i].z * rs * gg.z + bv.z;
    float y3 = v[i].w * rs * gg.w + bv.w;
    if (outf32) {
      float4 ov = {y0, y1, y2, y3};
      *(float4*)(of + (size_t)row * DM + c) = ov;
    } else {
      union { bf16 h[4]; uint2 u; } t;
      t.h[0] = __float2bfloat16(y0); t.h[1] = __float2bfloat16(y1);
      t.h[2] = __float2bfloat16(y2); t.h[3] = __float2bfloat16(y3);
      *(uint2*)(ob + (size_t)row * DM + c) = t.u;
    }
  }
}

template<int OUTF32>
__global__ __launch_bounds__(256) void ln_kernel(const float* __restrict__ x,
                                                 const float* __restrict__ g,
                                                 const float* __restrict__ bb,
                                                 bf16* __restrict__ ob,
                                                 float* __restrict__ of) {
  int wv = threadIdx.x >> 6, lane = threadIdx.x & 63;
  int row = blockIdx.x * 4 + wv;
  const float4* xr = (const float4*)(x + (size_t)row * DM);
  float4 v[4];
  #pragma unroll
  for (int i = 0; i < 4; ++i) v[i] = xr[lane + i * 64];
  ln_wave(v, g, bb, row, lane, ob, of, OUTF32);
}

// x += p + bias (single bf16 proj partial), write x back, then LN
template<int OUTF32>
__global__ __launch_bounds__(256) void ln_fused1(float* __restrict__ x,
                                                 const bf16* __restrict__ p,
                                                 const float* __restrict__ bias,
                                                 const float* __restrict__ g,
                                                 const float* __restrict__ bb,
                                                 bf16* __restrict__ ob,
                                                 float* __restrict__ of) {
  int wv = threadIdx.x >> 6, lane = threadIdx.x & 63;
  int row = blockIdx.x * 4 + wv;
  size_t rb = (size_t)row * DM;
  float4 v[4];
  #pragma unroll
  for (int i = 0; i < 4; ++i) {
    int c = (lane + i * 64) * 4;
    float4 xv = *(const float4*)(x + rb + c);
    float4 a0 = ld_bf16x4(p + rb + c);
    float4 bv = *(const float4*)(bias + c);
    xv.x += a0.x + bv.x;
    xv.y += a0.y + bv.y;
    xv.z += a0.z + bv.z;
    xv.w += a0.w + bv.w;
    *(float4*)(x + rb + c) = xv;
    v[i] = xv;
  }
  ln_wave(v, g, bb, row, lane, ob, of, OUTF32);
}

// x += p0+p1+p2+p3 + bias (bf16 split-K=4 partials), write x back, then LN
template<int OUTF32>
__global__ __launch_bounds__(256) void ln_fused4(float* __restrict__ x,
                                                 const bf16* __restrict__ p,
                                                 const float* __restrict__ bias,
                                                 const float* __restrict__ g,
                                                 const float* __restrict__ bb,
                                                 bf16* __restrict__ ob,
                                                 float* __restrict__ of) {
  int wv = threadIdx.x >> 6, lane = threadIdx.x & 63;
  int row = blockIdx.x * 4 + wv;
  size_t rb = (size_t)row * DM;
  const size_t NM = (size_t)NTOK * DM;
  float4 v[4];
  #pragma unroll
  for (int i = 0; i < 4; ++i) {
    int c = (lane + i * 64) * 4;
    float4 xv = *(const float4*)(x + rb + c);
    float4 a0 = ld_bf16x4(p + rb + c);
    float4 a1 = ld_bf16x4(p + NM + rb + c);
    float4 a2 = ld_bf16x4(p + 2*NM + rb + c);
    float4 a3 = ld_bf16x4(p + 3*NM + rb + c);
    float4 bv = *(const float4*)(bias + c);
    xv.x += a0.x + a1.x + a2.x + a3.x + bv.x;
    xv.y += a0.y + a1.y + a2.y + a3.y + bv.y;
    xv.z += a0.z + a1.z + a2.z + a3.z + bv.z;
    xv.w += a0.w + a1.w + a2.w + a3.w + bv.w;
    *(float4*)(x + rb + c) = xv;
    v[i] = xv;
  }
  ln_wave(v, g, bb, row, lane, ob, of, OUTF32);
}

// ---------------- small GEMM: 128 x 64 tile, 4 waves (proven R5 pipeline) ----
// EPI 0: bf16 out, +bias[col]
// EPI 4: bf16 partial Cb[row,col] = acc  (bias folded into ln_fused1)
template<int EPI>
__global__ __launch_bounds__(256) void gemm_bt(const bf16* __restrict__ A,
                                               const bf16* __restrict__ Bt,
                                               const float* __restrict__ bias,
                                               bf16* __restrict__ Cb,
                                               float* __restrict__ Cf,
                                               int M, int N, int K) {
  constexpr int BN = 64, NFR = 2;
  __shared__ bf16 As[3][128 * 32];
  __shared__ bf16 Bs[3][BN * 32];
  int tid = threadIdx.x;
  int wave = tid >> 6, lane = tid & 63;
  int l4 = lane & 15, lhi = lane >> 4;
  int wr = wave >> 1, wc = wave & 1;
  int nwg = gridDim.x * gridDim.y;
  int bid = blockIdx.y * gridDim.x + blockIdx.x;
  int cpx = nwg >> 3;
  int swz = (bid & 7) * cpx + (bid >> 3);
  int bx = swz % gridDim.x, by = swz / gridDim.x;
  int brow = by * 128, bcol = bx * BN;
  f32x4 acc[4][NFR] = {};
  int srow = lane >> 2;
  int scol = (lane & 3) * 8;
  int T = K >> 5;

  auto stage = [&](int buf, int t) {
    int k0 = t * 32;
    #pragma unroll
    for (int i = 0; i < 2; ++i) {
      int rb = i * 64 + wave * 16;
      gl_lds16(A + (size_t)(brow + rb + srow) * K + k0 + scol, &As[buf][rb * 32]);
    }
    int rb = wave * 16;
    gl_lds16(Bt + (size_t)(bcol + rb + srow) * K + k0 + scol, &Bs[buf][rb * 32]);
  };
  auto compute = [&](int buf) {
    bf16x8 af[4], bfv[NFR];
    #pragma unroll
    for (int m = 0; m < 4; ++m)
      af[m] = *(const bf16x8*)&As[buf][(wr * 64 + m * 16 + l4) * 32 + lhi * 8];
    #pragma unroll
    for (int n = 0; n < NFR; ++n)
      bfv[n] = *(const bf16x8*)&Bs[buf][(wc * 32 + n * 16 + l4) * 32 + lhi * 8];
    #pragma unroll
    for (int m = 0; m < 4; ++m)
      #pragma unroll
      for (int n = 0; n < NFR; ++n)
        acc[m][n] = __builtin_amdgcn_mfma_f32_16x16x32_bf16(af[m], bfv[n], acc[m][n], 0, 0, 0);
  };

  stage(0, 0);
  stage(1, 1);
  for (int t = 0; t < T; ++t) {
    if (t < T - 1) asm volatile("s_waitcnt vmcnt(3)" ::: "memory");
    else           asm volatile("s_waitcnt vmcnt(0)" ::: "memory");
    __builtin_amdgcn_s_barrier();
    asm volatile("" ::: "memory");
    if (t + 2 < T) stage((t + 2) % 3, t + 2);
    compute(t % 3);
  }

  #pragma unroll
  for (int m = 0; m < 4; ++m) {
    int row0 = brow + wr * 64 + m * 16 + lhi * 4;
    #pragma unroll
    for (int n = 0; n < NFR; ++n) {
      int col = bcol + wc * 32 + n * 16 + l4;
      #pragma unroll
      for (int r = 0; r < 4; ++r) {
        int row = row0 + r;
        float v = acc[m][n][r];
        if (EPI == 0) {
          v += bias[col];
          Cb[(size_t)row * N + col] = __float2bfloat16(v);
        } else {
          Cb[(size_t)row * N + col] = __float2bfloat16(v);
        }
      }
    }
  }
}

// ---------------- 8-phase 256x256 GEMM body (pipelined subtile reads) --------
// EPI 0: bf16 +bias[col]; 1: +relu; 4: bf16 split-K partial; 5/6: enc remaps.
template<int EPI>
__device__ __forceinline__ void gemm8x_body(bf16 (*S)[8192],
                                            const bf16* __restrict__ A,
                                            const bf16* __restrict__ Bt,
                                            const float* __restrict__ bias,
                                            bf16* __restrict__ Cb,
                                            float* __restrict__ Cf,
                                            int M, int N, int K,
                                            int bx, int by, int kz) {
  int tid = threadIdx.x;
  int wave = tid >> 6, lane = tid & 63;
  int l4 = lane & 15, lhi = lane >> 4;
  int wr = wave >> 2, wc = wave & 3;
  int brow = by * 256, bcol = bx * 256;
  f32x4 acc[8][4] = {};

  int kbase = 0, Keff = K;
  if (EPI == 4) { Keff = K >> 2; kbase = kz * Keff; }
  int T = Keff >> 6;   // K-tiles of 64

  int srcRow = tid >> 3;
  int srcKb  = ((tid & 7) << 4) ^ (((tid >> 5) & 1) << 5) ^ (((tid >> 4) & 1) << 6);
  int swzr   = (((l4 >> 2) & 1) << 4) ^ (((l4 >> 1) & 1) << 5);

  auto stageA = [&](int d, int half, int kt) {
    #pragma unroll
    for (int j = 0; j < 2; ++j) {
      int r = brow + half * 128 + j * 64 + srcRow;
      if (EPI == 6) r = ((r >> 10) << 12) + 2048 + (r & 1023);
      const char* src = (const char*)(A + (size_t)r * K + kbase + kt * 64) + srcKb;
      gl_lds16(src, (char*)&S[d * 2 + half][0] + j * 8192 + wave * 1024);
    }
  };
  auto stageB = [&](int d, int half, int kt) {
    #pragma unroll
    for (int j = 0; j < 2; ++j) {
      int r = bcol + half * 128 + j * 64 + srcRow;
      if (EPI == 5) r = ((r >> 10) << 12) + 1024 + (r & 1023);
      const char* src = (const char*)(Bt + (size_t)r * K + kbase + kt * 64) + srcKb;
      gl_lds16(src, (char*)&S[4 + d * 2 + half][0] + j * 8192 + wave * 1024);
    }
  };

  stageA(0, 0, 0); stageA(0, 1, 0); stageB(0, 0, 0); stageB(0, 1, 0);

  for (int i = 0; i < T; ++i) {
    int d = i & 1, od = d ^ 1;
    asm volatile("s_waitcnt vmcnt(0)" ::: "memory");
    __builtin_amdgcn_s_barrier();
    asm volatile("" ::: "memory");
    const bf16* As_ = &S[d * 2 + wr][0];
    const bf16* Bs_ = &S[4 + d * 2 + (wc >> 1)][0];
    int rB = (wc & 1) * 64;
    bool st = (i + 1) < T;

    bf16x8 bfv[4][2];
    #pragma unroll
    for (int n = 0; n < 4; ++n) {
      int r = rB + n * 16 + l4;
      #pragma unroll
      for (int ks = 0; ks < 2; ++ks)
        bfv[n][ks] = *(const bf16x8*)&Bs_[r * 64 + ((ks * 32 + lhi * 8) ^ swzr)];
    }
    bf16x8 afA[2][2], afB[2][2];
    #pragma unroll
    for (int mm = 0; mm < 2; ++mm) {
      int r = mm * 16 + l4;
      #pragma unroll
      for (int ks = 0; ks < 2; ++ks)
        afA[mm][ks] = *(const bf16x8*)&As_[r * 64 + ((ks * 32 + lhi * 8) ^ swzr)];
    }
    if (st) { stageA(od, 0, i + 1); stageA(od, 1, i + 1); }

    // q0
    #pragma unroll
    for (int mm = 0; mm < 2; ++mm) {
      int r = (2 + mm) * 16 + l4;
      #pragma unroll
      for (int ks = 0; ks < 2; ++ks)
        afB[mm][ks] = *(const bf16x8*)&As_[r * 64 + ((ks * 32 + lhi * 8) ^ swzr)];
    }
    if (st) { stageB(od, 0, i + 1); stageB(od, 1, i + 1); }
    __builtin_amdgcn_s_setprio(1);
    #pragma unroll
    for (int mm = 0; mm < 2; ++mm)
      #pragma unroll
      for (int ks = 0; ks < 2; ++ks)
        #pragma unroll
        for (int n = 0; n < 4; ++n)
          acc[mm][n] = __builtin_amdgcn_mfma_f32_16x16x32_bf16(afA[mm][ks], bfv[n][ks], acc[mm][n], 0, 0, 0);
    __builtin_amdgcn_s_setprio(0);

    // q1
    #pragma unroll
    for (int mm = 0; mm < 2; ++mm) {
      int r = (4 + mm) * 16 + l4;
      #pragma unroll
      for (int ks = 0; ks < 2; ++ks)
        afA[mm][ks] = *(const bf16x8*)&As_[r * 64 + ((ks * 32 + lhi * 8) ^ swzr)];
    }
    __builtin_amdgcn_s_setprio(1);
    #pragma unroll
    for (int mm = 0; mm < 2; ++mm)
      #pragma unroll
      for (int ks = 0; ks < 2; ++ks)
        #pragma unroll
        for (int n = 0; n < 4; ++n)
          acc[2 + mm][n] = __builtin_amdgcn_mfma_f32_16x16x32_bf16(afB[mm][ks], bfv[n][ks], acc[2 + mm][n], 0, 0, 0);
    __builtin_amdgcn_s_setprio(0);

    // q2
    #pragma unroll
    for (int mm = 0; mm < 2; ++mm) {
      int r = (6 + mm) * 16 + l4;
      #pragma unroll
      for (int ks = 0; ks < 2; ++ks)
        afB[mm][ks] = *(const bf16x8*)&As_[r * 64 + ((ks * 32 + lhi * 8) ^ swzr)];
    }
    __builtin_amdgcn_s_setprio(1);
    #pragma unroll
    for (int mm = 0; mm < 2; ++mm)
      #pragma unroll
      for (int ks = 0; ks < 2; ++ks)
        #pragma unroll
        for (int n = 0; n < 4; ++n)
          acc[4 + mm][n] = __builtin_amdgcn_mfma_f32_16x16x32_bf16(afA[mm][ks], bfv[n][ks], acc[4 + mm][n], 0, 0, 0);
    __builtin_amdgcn_s_setprio(0);

    // q3
    __builtin_amdgcn_s_setprio(1);
    #pragma unroll
    for (int mm = 0; mm < 2; ++mm)
      #pragma unroll
      for (int ks = 0; ks < 2; ++ks)
        #pragma unroll
        for (int n = 0; n < 4; ++n)
          acc[6 + mm][n] = __builtin_amdgcn_mfma_f32_16x16x32_bf16(afB[mm][ks], bfv[n][ks], acc[6 + mm][n], 0, 0, 0);
    __builtin_amdgcn_s_setprio(0);
    asm volatile("" ::: "memory");
  }

  #pragma unroll
  for (int m = 0; m < 8; ++m) {
    int row0 = brow + wr * 128 + m * 16 + lhi * 4;
    #pragma unroll
    for (int n = 0; n < 4; ++n) {
      int col = bcol + wc * 64 + n * 16 + l4;
      #pragma unroll
      for (int r = 0; r < 4; ++r) {
        int row = row0 + r;
        float v = acc[m][n][r];
        if (EPI == 0) {
          v += bias[col];
          Cb[(size_t)row * N + col] = __float2bfloat16(v);
        } else if (EPI == 1) {
          v += bias[col];
          v = fmaxf(v, 0.0f);
          Cb[(size_t)row * N + col] = __float2bfloat16(v);
        } else if (EPI == 4) {
          ((bf16*)Cf)[(size_t)kz * ((size_t)M * N) + (size_t)row * N + col] = __float2bfloat16(v);
        } else if (EPI == 5) {
          v += bias[((col >> 10) << 12) + 1024 + (col & 1023)];
          Cb[(size_t)row * N + col] = __float2bfloat16(v);
        } else {
          v += bias[((row >> 10) << 12) + 2048 + (row & 1023)];
          Cb[(size_t)row * N + col] = __float2bfloat16(v);
        }
      }
    }
  }
}

template<int EPI>
__global__ __launch_bounds__(512, 2) void gemm8x(const bf16* __restrict__ A,
                                                 const bf16* __restrict__ Bt,
                                                 const float* __restrict__ bias,
                                                 bf16* __restrict__ Cb,
                                                 float* __restrict__ Cf,
                                                 int M, int N, int K) {
  __shared__ bf16 S[8][8192];
  int nwg = gridDim.x * gridDim.y;
  int bid = blockIdx.y * gridDim.x + blockIdx.x;
  int cpx = nwg >> 3;
  int swz = (bid & 7) * cpx + (bid >> 3);
  int bx = swz % gridDim.x, by = swz / gridDim.x;
  gemm8x_body<EPI>(S, A, Bt, bias, Cb, Cf, M, N, K, bx, by, blockIdx.z);
}

// merged hoisted encoder K / V^T projections: 768 blocks = 3 exact rounds
__global__ __launch_bounds__(512, 2) void gemm8x_dual(const bf16* __restrict__ encb,
                                                      const bf16* __restrict__ wca,
                                                      const float* __restrict__ cab,
                                                      bf16* __restrict__ keall,
                                                      bf16* __restrict__ vteall) {
  __shared__ bf16 S[8][8192];
  int bid = blockIdx.x;
  if (bid < 384) {                               // K_enc: grid 24 x 16
    int swz = (bid & 7) * 48 + (bid >> 3);
    int bx = swz % 24, by = swz / 24;
    gemm8x_body<5>(S, encb, wca, cab, keall, nullptr, NTOK, NL*DM, DM, bx, by, 0);
  } else {                                       // V_enc^T: grid 16 x 24
    int b2 = bid - 384;
    int swz = (b2 & 7) * 48 + (b2 >> 3);
    int bx = swz % 16, by = swz / 16;
    gemm8x_body<6>(S, wca, encb, cab, vteall, nullptr, NL*DM, NTOK, DM, bx, by, 0);
  }
}

// ---------------- QKV GEMM: 256x192 tiles, grid 16x16 = 256 = exact fill -----
// 8 waves (2M x 4N), per-wave 128x48 (acc[8][3]). B = 3 x 64-row subtiles.
// Same both-sides swizzle as gemm8x. V columns (col >= 2048) written
// TRANSPOSED to vtbuf (boundary is 16-aligned -> fragment-uniform branch).
__global__ __launch_bounds__(512, 1) void gemm_qkv(const bf16* __restrict__ A,
                                                   const bf16* __restrict__ Bt,
                                                   const float* __restrict__ bias,
                                                   bf16* __restrict__ qkv,
                                                   bf16* __restrict__ vt) {
  __shared__ bf16 SA[4][8192];     // [dbuf*2+half][128x64]
  __shared__ bf16 SB[2][12288];    // [dbuf][192x64]
  constexpr int K = DM, N = 3 * DM, T = DM / 64;
  int tid = threadIdx.x;
  int wave = tid >> 6, lane = tid & 63;
  int l4 = lane & 15, lhi = lane >> 4;
  int wr = wave >> 2, wc = wave & 3;
  int bid = blockIdx.x;
  int swz = (bid & 7) * 32 + (bid >> 3);
  int bx = swz & 15, by = swz >> 4;
  int brow = by * 256, bcol = bx * 192;
  f32x4 acc[8][3] = {};

  int srcRow = tid >> 3;
  int srcKb  = ((tid & 7) << 4) ^ (((tid >> 5) & 1) << 5) ^ (((tid >> 4) & 1) << 6);
  int swzr   = (((l4 >> 2) & 1) << 4) ^ (((l4 >> 1) & 1) << 5);

  auto stageA = [&](int d, int half, int kt) {
    #pragma unroll
    for (int j = 0; j < 2; ++j) {
      int r = brow + half * 128 + j * 64 + srcRow;
      const char* src = (const char*)(A + (size_t)r * K + kt * 64) + srcKb;
      gl_lds16(src, (char*)&SA[d * 2 + half][0] + j * 8192 + wave * 1024);
    }
  };
  auto stageB = [&](int d, int sub, int kt) {
    int r = bcol + sub * 64 + srcRow;
    const char* src = (const char*)(Bt + (size_t)r * K + kt * 64) + srcKb;
    gl_lds16(src, (char*)&SB[d][0] + sub * 8192 + wave * 1024);
  };

  stageA(0, 0, 0); stageA(0, 1, 0);
  stageB(0, 0, 0); stageB(0, 1, 0); stageB(0, 2, 0);

  for (int i = 0; i < T; ++i) {
    int d = i & 1, od = d ^ 1;
    asm volatile("s_waitcnt vmcnt(0)" ::: "memory");
    __builtin_amdgcn_s_barrier();
    asm volatile("" ::: "memory");
    const bf16* As_ = &SA[d * 2 + wr][0];
    const bf16* Bs_ = &SB[d][0];
    bool st = (i + 1) < T;

    bf16x8 bfv[3][2];
    #pragma unroll
    for (int n = 0; n < 3; ++n) {
      int r = wc * 48 + n * 16 + l4;
      #pragma unroll
      for (int ks = 0; ks < 2; ++ks)
        bfv[n][ks] = *(const bf16x8*)&Bs_[r * 64 + ((ks * 32 + lhi * 8) ^ swzr)];
    }
    bf16x8 afA[2][2], afB[2][2];
    #pragma unroll
    for (int mm = 0; mm < 2; ++mm) {
      int r = mm * 16 + l4;
      #pragma unroll
      for (int ks = 0; ks < 2; ++ks)
        afA[mm][ks] = *(const bf16x8*)&As_[r * 64 + ((ks * 32 + lhi * 8) ^ swzr)];
    }
    if (st) { stageA(od, 0, i + 1); stageA(od, 1, i + 1); }

    // q0
    #pragma unroll
    for (int mm = 0; mm < 2; ++mm) {
      int r = (2 + mm) * 16 + l4;
      #pragma unroll
      for (int ks = 0; ks < 2; ++ks)
        afB[mm][ks] = *(const bf16x8*)&As_[r * 64 + ((ks * 32 + lhi * 8) ^ swzr)];
    }
    if (st) { stageB(od, 0, i + 1); stageB(od, 1, i + 1); stageB(od, 2, i + 1); }
    __builtin_amdgcn_s_setprio(1);
    #pragma unroll
    for (int mm = 0; mm < 2; ++mm)
      #pragma unroll
      for (int ks = 0; ks < 2; ++ks)
        #pragma unroll
        for (int n = 0; n < 3; ++n)
          acc[mm][n] = __builtin_amdgcn_mfma_f32_16x16x32_bf16(afA[mm][ks], bfv[n][ks], acc[mm][n], 0, 0, 0);
    __builtin_amdgcn_s_setprio(0);

    // q1
    #pragma unroll
    for (int mm = 0; mm < 2; ++mm) {
      int r = (4 + mm) * 16 + l4;
      #pragma unroll
      for (int ks = 0; ks < 2; ++ks)
        afA[mm][ks] = *(const bf16x8*)&As_[r * 64 + ((ks * 32 + lhi * 8) ^ swzr)];
    }
    __builtin_amdgcn_s_setprio(1);
    #pragma unroll
    for (int mm = 0; mm < 2; ++mm)
      #pragma unroll
      for (int ks = 0; ks < 2; ++ks)
        #pragma unroll
        for (int n = 0; n < 3; ++n)
          acc[2 + mm][n] = __builtin_amdgcn_mfma_f32_16x16x32_bf16(afB[mm][ks], bfv[n][ks], acc[2 + mm][n], 0, 0, 0);
    __builtin_amdgcn_s_setprio(0);

    // q2
    #pragma unroll
    for (int mm = 0; mm < 2; ++mm) {
      int r = (6 + mm) * 16 + l4;
      #pragma unroll
      for (int ks = 0; ks < 2; ++ks)
        afB[mm][ks] = *(const bf16x8*)&As_[r * 64 + ((ks * 32 + lhi * 8) ^ swzr)];
    }
    __builtin_amdgcn_s_setprio(1);
    #pragma unroll
    for (int mm = 0; mm < 2; ++mm)
      #pragma unroll
      for (int ks = 0; ks < 2; ++ks)
        #pragma unroll
        for (int n = 0; n < 3; ++n)
          acc[4 + mm][n] = __builtin_amdgcn_mfma_f32_16x16x32_bf16(afA[mm][ks], bfv[n][ks], acc[4 + mm][n], 0, 0, 0);
    __builtin_amdgcn_s_setprio(0);

    // q3
    __builtin_amdgcn_s_setprio(1);
    #pragma unroll
    for (int mm = 0; mm < 2; ++mm)
      #pragma unroll
      for (int ks = 0; ks < 2; ++ks)
        #pragma unroll
        for (int n = 0; n < 3; ++n)
          acc[6 + mm][n] = __builtin_amdgcn_mfma_f32_16x16x32_bf16(afB[mm][ks], bfv[n][ks], acc[6 + mm][n], 0, 0, 0);
    __builtin_amdgcn_s_setprio(0);
    asm volatile("" ::: "memory");
  }

  #pragma unroll
  for (int m = 0; m < 8; ++m) {
    int row0 = brow + wr * 128 + m * 16 + lhi * 4;
    #pragma unroll
    for (int n = 0; n < 3; ++n) {
      int col = bcol + wc * 48 + n * 16 + l4;   // fragment entirely on one side of 2048
      float bv = bias[col];
      if (col >= 2048) {
        union { bf16 h[4]; uint2 u; } t;
        #pragma unroll
        for (int r = 0; r < 4; ++r)
          t.h[r] = __float2bfloat16(acc[m][n][r] + bv);
        *(uint2*)(vt + (size_t)(col - 2048) * NTOK + row0) = t.u;
      } else {
        #pragma unroll
        for (int r = 0; r < 4; ++r)
          qkv[(size_t)(row0 + r) * N + col] = __float2bfloat16(acc[m][n][r] + bv);
      }
    }
  }
}

// ---------------- fused attention (LDS-staged 64-key tiles + XCD swizzle) ----
template<int CAUSAL>
__global__ __launch_bounds__(256, 2) void attn_kernel(const bf16* __restrict__ qg,
                                                      const bf16* __restrict__ kg,
                                                      const bf16* __restrict__ vtg,
                                                      bf16* __restrict__ og,
                                                      int qs, int ks) {
  __shared__ bf16 P[4][16][520];   // 66,560 B
  __shared__ bf16 KV[4096];        // 8 KB tile: [64 rows][128 B]
  int nwg = gridDim.x * gridDim.y;           // 1024
  int lin = blockIdx.y * gridDim.x + blockIdx.x;
  int swzb = (lin & 7) * (nwg >> 3) + (lin >> 3);
  int qblk = swzb & 7;                        // gridDim.x == 8
  int bh = swzb >> 3;
  int b = bh >> 4, h = bh & 15;
  int wave = threadIdx.x >> 6, lane = threadIdx.x & 63;
  int l4 = lane & 15, lhi = lane >> 4;
  int qbase = qblk * 64 + wave * 16;
  const int qmax = CAUSAL ? (qbase + 15) : 0x7fffffff;    // wave-uniform
  const int tmaxb = CAUSAL ? qblk : 7;                     // block-uniform

  int srow8 = lane >> 3;
  int sbyte = ((lane & 7) * 16) ^ (srow8 << 4);            // pre-swizzled source byte
  int rdswz = (l4 & 7) << 4;                               // read-side XOR

  bf16x8 qa[2];
  {
    size_t qrow = (size_t)(b * SEQL + qbase + l4);
    #pragma unroll
    for (int kk = 0; kk < 2; ++kk)
      qa[kk] = *(const bf16x8*)&qg[qrow * qs + h * HD + kk * 32 + lhi * 8];
  }

  // ---- QK^T over 8 staged 64-key tiles ----
  f32x4 acc[32] = {};
  #pragma unroll
  for (int t = 0; t < 8; ++t) {
    if (t <= tmaxb) {
      #pragma unroll
      for (int j = 0; j < 2; ++j) {
        int row = (wave * 2 + j) * 8 + srow8;
        const char* src = (const char*)(kg + (size_t)(b * SEQL + t * 64 + row) * ks + h * HD) + sbyte;
        gl_lds16(src, (char*)&KV[0] + (wave * 2 + j) * 1024);
      }
      asm volatile("s_waitcnt vmcnt(0)" ::: "memory");
      __builtin_amdgcn_s_barrier();
      asm volatile("" ::: "memory");
      #pragma unroll
      for (int n = 0; n < 4; ++n) {
        int nk = t * 4 + n;
        if (!CAUSAL || nk * 16 <= qmax) {
          #pragma unroll
          for (int kk = 0; kk < 2; ++kk) {
            bf16x8 kf = *(const bf16x8*)((const char*)&KV[0] + (n * 16 + l4) * 128 + ((kk * 64 + lhi * 16) ^ rdswz));
            acc[nk] = __builtin_amdgcn_mfma_f32_16x16x32_bf16(qa[kk], kf, acc[nk], 0, 0, 0);
          }
        }
      }
      __builtin_amdgcn_s_barrier();
      asm volatile("" ::: "memory");
    }
  }

  // ---- softmax ----
  int qloc = qbase + lhi * 4;
  #pragma unroll
  for (int r = 0; r < 4; ++r) {
    float mx = -3.0e38f;
    #pragma unroll
    for (int n = 0; n < 32; ++n) {
      float sv = acc[n][r] * 0.125f;
      if (CAUSAL && (n * 16 + l4 > qloc + r)) sv = -3.0e38f;
      acc[n][r] = sv;
      mx = fmaxf(mx, sv);
    }
    #pragma unroll
    for (int o = 1; o < 16; o <<= 1) mx = fmaxf(mx, __shfl_xor(mx, o));
    float sum = 0.0f;
    #pragma unroll
    for (int n = 0; n < 32; ++n) {
      float p;
      if (CAUSAL && n * 16 > qmax) p = 0.0f;
      else p = __expf(acc[n][r] - mx);
      acc[n][r] = p;
      sum += p;
    }
    #pragma unroll
    for (int o = 1; o < 16; o <<= 1) sum += __shfl_xor(sum, o);
    float rcp = 1.0f / sum;
    #pragma unroll
    for (int n = 0; n < 32; ++n)
      P[wave][lhi * 4 + r][n * 16 + l4] = __float2bfloat16(acc[n][r] * rcp);
  }
  __syncthreads();

  // ---- PV over 8 staged 64-key V^T tiles (reuse KV buffer) ----
  f32x4 oacc[4] = {};
  #pragma unroll
  for (int t = 0; t < 8; ++t) {
    if (t <= tmaxb) {
      #pragma unroll
      for (int j = 0; j < 2; ++j) {
        int row = (wave * 2 + j) * 8 + srow8;
        const char* src = (const char*)(vtg + (size_t)(h * HD + row) * NTOK + b * SEQL + t * 64) + sbyte;
        gl_lds16(src, (char*)&KV[0] + (wave * 2 + j) * 1024);
      }
      asm volatile("s_waitcnt vmcnt(0)" ::: "memory");
      __builtin_amdgcn_s_barrier();
      asm volatile("" ::: "memory");
      #pragma unroll
      for (int ksl = 0; ksl < 2; ++ksl) {
        int kslot = t * 2 + ksl;
        if (!CAUSAL || kslot * 32 <= qmax) {
          bf16x8 pa = *(const bf16x8*)&P[wave][l4][kslot * 32 + lhi * 8];
          #pragma unroll
          for (int nn = 0; nn < 4; ++nn) {
            bf16x8 vf = *(const bf16x8*)((const char*)&KV[0] + (nn * 16 + l4) * 128 + ((ksl * 64 + lhi * 16) ^ rdswz));
            oacc[nn] = __builtin_amdgcn_mfma_f32_16x16x32_bf16(pa, vf, oacc[nn], 0, 0, 0);
          }
        }
      }
      __builtin_amdgcn_s_barrier();
      asm volatile("" ::: "memory");
    }
  }

  size_t orow = (size_t)(b * SEQL + qbase + lhi * 4);
  #pragma unroll
  for (int n = 0; n < 4; ++n)
    #pragma unroll
    for (int r = 0; r < 4; ++r)
      og[(orow + r) * DM + h * HD + n * 16 + l4] = __float2bfloat16(oacc[n][r]);
}

// ---------------- host ----------------
extern "C" void kernel_launch(void* const* d_in, const int* in_sizes, int n_in,
                              void* d_out, int out_size, void* d_ws, size_t ws_size,
                              hipStream_t stream) {
  (void)in_sizes; (void)n_in; (void)out_size;
  const float* enc   = (const float*)d_in[0];
  const int*   toks  = (const int*)  d_in[1];
  const float* table = (const float*)d_in[4];
  const float* sa_w  = (const float*)d_in[5];
  const float* sa_b  = (const float*)d_in[6];
  const float* ca_w  = (const float*)d_in[7];
  const float* ca_b  = (const float*)d_in[8];
  const float* f1w   = (const float*)d_in[9];
  const float* f1b   = (const float*)d_in[10];
  const float* f2w   = (const float*)d_in[11];
  const float* f2b   = (const float*)d_in[12];
  const float* lng   = (const float*)d_in[13];
  const float* lnbp  = (const float*)d_in[14];
  const float* fg    = (const float*)d_in[15];
  const float* fbp   = (const float*)d_in[16];
  float* outp = (float*)d_out;

  char* base = (char*)d_ws;
  size_t off = 0;
  auto alloc = [&](size_t nbytes) -> char* {
    char* p = base + off;
    off += (nbytes + 255) & ~(size_t)255;
    return p;
  };
  const size_t DDb = (size_t)DM * DM;
  bf16* wt_sa   = (bf16*)alloc((size_t)NL * 4 * DDb * 2);
  bf16* wt_ca   = (bf16*)alloc((size_t)NL * 4 * DDb * 2);
  bf16* wt_f1   = (bf16*)alloc((size_t)NL * FF * DM * 2);
  bf16* wt_f2   = (bf16*)alloc((size_t)NL * FF * DM * 2);
  bf16* encb    = (bf16*)alloc((size_t)NTOK * DM * 2);
  bf16* keall   = (bf16*)alloc((size_t)NTOK * NL * DM * 2);   // [4096][6144]
  bf16* vteall  = (bf16*)alloc((size_t)NL * DM * NTOK * 2);   // [6144][4096]
  bf16* hbuf    = (bf16*)alloc((size_t)NTOK * DM * 2);
  bf16* qkvbuf  = (bf16*)alloc((size_t)NTOK * 3 * DM * 2);    // fused Q|K|V (stride 3072)
  bf16* vtbuf   = (bf16*)alloc((size_t)NTOK * DM * 2);
  bf16* aobuf   = (bf16*)alloc((size_t)NTOK * DM * 2);
  bf16* h1buf   = (bf16*)alloc((size_t)NTOK * FF * 2);
  float* xbuf   = (float*)alloc((size_t)NTOK * DM * 4);
  bf16* pbuf4   = (bf16*)alloc((size_t)4 * NTOK * DM * 2);    // bf16 split-K / proj partials
  if (off > ws_size) return;

  transpose_cvt<<<dim3(DM/64, DM/64, NL*4), 256, 0, stream>>>(sa_w, wt_sa, DM, DM);
  transpose_cvt<<<dim3(DM/64, DM/64, NL*4), 256, 0, stream>>>(ca_w, wt_ca, DM, DM);
  transpose_cvt<<<dim3(FF/64, DM/64, NL),   256, 0, stream>>>(f1w, wt_f1, DM, FF);
  transpose_cvt<<<dim3(DM/64, FF/64, NL),   256, 0, stream>>>(f2w, wt_f2, FF, DM);
  cvt_bf16<<<(NTOK * DM / 4) / 256, 256, 0, stream>>>(enc, encb);
  embed_pe<<<NTOK, 256, 0, stream>>>(toks, table, xbuf);

  // merged hoisted all-layer encoder K / V^T projections (768 blocks = 3 rounds)
  gemm8x_dual<<<768, 512, 0, stream>>>(encb, wt_ca, ca_b, keall, vteall);

  // layer-0 pre-norm (later ones fused into proj / FFN2 reduces)
  ln_kernel<0><<<NTOK/4, 256, 0, stream>>>(xbuf, lng + 0*DM, lnbp + 0*DM, hbuf, nullptr);

  for (int l = 0; l < NL; ++l) {
    const bf16* wsa = wt_sa + (size_t)l * 4 * DDb;
    const bf16* wca = wt_ca + (size_t)l * 4 * DDb;
    const float* bsa = sa_b + (size_t)l * 4 * DM;
    const float* bca = ca_b + (size_t)l * 4 * DM;
    // ---- self-attention: fused QKV (256x192 tiles, exact fill) ----
    gemm_qkv<<<256, 512, 0, stream>>>(hbuf, wsa, bsa, qkvbuf, vtbuf);
    attn_kernel<1><<<dim3(SEQL/64, NB_*NH), 256, 0, stream>>>(qkvbuf, qkvbuf + DM, vtbuf, aobuf, 3*DM, 3*DM);
    gemm_bt<4><<<dim3(DM/64, NTOK/128), 256, 0, stream>>>(aobuf, wsa + 3*DDb, nullptr, pbuf4, nullptr, NTOK, DM, DM);
    ln_fused1<0><<<NTOK/4, 256, 0, stream>>>(xbuf, pbuf4, bsa + 3*DM,
                                             lng + (l*3+1)*DM, lnbp + (l*3+1)*DM, hbuf, nullptr);
    // ---- cross-attention ----
    gemm_bt<0><<<dim3(DM/64, NTOK/128), 256, 0, stream>>>(hbuf, wca + 0*DDb, bca + 0*DM, qkvbuf, nullptr, NTOK, DM, DM);
    attn_kernel<0><<<dim3(SEQL/64, NB_*NH), 256, 0, stream>>>(qkvbuf, keall + l*DM, vteall + (size_t)l*DM*NTOK, aobuf, DM, NL*DM);
    gemm_bt<4><<<dim3(DM/64, NTOK/128), 256, 0, stream>>>(aobuf, wca + 3*DDb, nullptr, pbuf4, nullptr, NTOK, DM, DM);
    ln_fused1<0><<<NTOK/4, 256, 0, stream>>>(xbuf, pbuf4, bca + 3*DM,
                                             lng + (l*3+2)*DM, lnbp + (l*3+2)*DM, hbuf, nullptr);
    // ---- FFN ----
    gemm8x<1><<<dim3(FF/256, NTOK/256), 512, 0, stream>>>(hbuf, wt_f1 + (size_t)l*FF*DM, f1b + (size_t)l*FF, h1buf, nullptr, NTOK, FF, DM);
    gemm8x<4><<<dim3(DM/256, NTOK/256, 4), 512, 0, stream>>>(h1buf, wt_f2 + (size_t)l*FF*DM, nullptr, nullptr, (float*)pbuf4, NTOK, DM, FF);
    if (l < NL - 1)
      ln_fused4<0><<<NTOK/4, 256, 0, stream>>>(xbuf, pbuf4, f2b + (size_t)l*DM,
                                               lng + ((l+1)*3+0)*DM, lnbp + ((l+1)*3+0)*DM, hbuf, nullptr);
    else
      ln_fused4<1><<<NTOK/4, 256, 0, stream>>>(xbuf, pbuf4, f2b + (size_t)l*DM,
                                               fg, fbp, nullptr, outp);
  }
}

// Round 24
// 1881.490 us; speedup vs baseline: 1.0053x; 1.0053x over previous
//
#include <hip/hip_runtime.h>
#include <hip/hip_bf16.h>

typedef __attribute__((ext_vector_type(8))) short bf16x8;
typedef __attribute__((ext_vector_type(4))) float f32x4;
typedef __hip_bfloat16 bf16;

constexpr int DM   = 1024;
constexpr int NH   = 16;
constexpr int HD   = 64;
constexpr int FF   = 4096;
constexpr int NL   = 6;
constexpr int NB_  = 8;
constexpr int SEQL = 512;
constexpr int NTOK = NB_ * SEQL;   // 4096

// ---------------- async global->LDS (16B) ----------------
__device__ __forceinline__ void gl_lds16(const void* g, void* l) {
  __builtin_amdgcn_global_load_lds(
      (const __attribute__((address_space(1))) unsigned int*)g,
      (__attribute__((address_space(3))) unsigned int*)l, 16, 0, 0);
}

__device__ __forceinline__ float4 ld_bf16x4(const bf16* p) {
  union { uint2 u; bf16 h[4]; } t;
  t.u = *(const uint2*)p;
  return make_float4(__bfloat162float(t.h[0]), __bfloat162float(t.h[1]),
                     __bfloat162float(t.h[2]), __bfloat162float(t.h[3]));
}

// ---------------- weight transpose + f32->bf16 (vectorized, 64x64 tiles) ----
__global__ __launch_bounds__(256) void transpose_cvt(const float* __restrict__ src,
                                                     bf16* __restrict__ dst,
                                                     int R, int C) {
  __shared__ float tile[64][65];
  size_t mo = (size_t)blockIdx.z * R * C;
  src += mo; dst += mo;
  int c0 = blockIdx.x * 64, r0 = blockIdx.y * 64;
  int t = threadIdx.x;
  int cq = (t & 15) * 4;
  int rw = t >> 4;
  #pragma unroll
  for (int p = 0; p < 4; ++p) {
    int row = rw + p * 16;
    float4 v = *(const float4*)(src + (size_t)(r0 + row) * C + c0 + cq);
    tile[row][cq]     = v.x;
    tile[row][cq + 1] = v.y;
    tile[row][cq + 2] = v.z;
    tile[row][cq + 3] = v.w;
  }
  __syncthreads();
  int rq = (t & 15) * 4;
  int cw = t >> 4;
  #pragma unroll
  for (int p = 0; p < 4; ++p) {
    int cc = cw + p * 16;
    union { bf16 h[4]; unsigned long long u; } o;
    o.h[0] = __float2bfloat16(tile[rq][cc]);
    o.h[1] = __float2bfloat16(tile[rq + 1][cc]);
    o.h[2] = __float2bfloat16(tile[rq + 2][cc]);
    o.h[3] = __float2bfloat16(tile[rq + 3][cc]);
    *(unsigned long long*)(dst + (size_t)(c0 + cc) * R + r0 + rq) = o.u;
  }
}

__global__ __launch_bounds__(256) void cvt_bf16(const float* __restrict__ s,
                                                bf16* __restrict__ d) {
  size_t i = (size_t)blockIdx.x * 256 + threadIdx.x;
  float4 v = ((const float4*)s)[i];
  union { bf16 h[4]; uint2 u; } t;
  t.h[0] = __float2bfloat16(v.x); t.h[1] = __float2bfloat16(v.y);
  t.h[2] = __float2bfloat16(v.z); t.h[3] = __float2bfloat16(v.w);
  *(uint2*)(d + i * 4) = t.u;
}

// ---------------- embedding + positional encoding ----------------
__global__ __launch_bounds__(256) void embed_pe(const int* __restrict__ tok,
                                                const float* __restrict__ table,
                                                float* __restrict__ x) {
  int t = blockIdx.x;
  int s = t & (SEQL - 1);
  int tk = tok[t];
  int d = threadIdx.x * 4;
  float4 e = *(const float4*)(table + (size_t)tk * DM + d);
  float o[4] = {e.x, e.y, e.z, e.w};
  const float NEGC = -9.210340371976184f / 1024.0f;   // -ln(10000)/D
  #pragma unroll
  for (int i = 0; i < 4; ++i) {
    int dd = d + i;
    float div = __expf((float)(dd & ~1) * NEGC);
    float arg = (float)s * div;
    float pe = (dd & 1) ? cosf(arg) : sinf(arg);
    o[i] = o[i] * 32.0f + pe;       // sqrt(1024)=32
  }
  float4 ov = {o[0], o[1], o[2], o[3]};
  *(float4*)(x + (size_t)t * DM + d) = ov;
}

// ---------------- layernorm: one ROW per WAVE ----------
__device__ __forceinline__ void ln_wave(float4 v[4], const float* __restrict__ g,
                                        const float* __restrict__ bb,
                                        int row, int lane, bf16* ob, float* of, int outf32) {
  float s = 0.0f;
  #pragma unroll
  for (int i = 0; i < 4; ++i) s += v[i].x + v[i].y + v[i].z + v[i].w;
  #pragma unroll
  for (int o = 32; o; o >>= 1) s += __shfl_xor(s, o);
  float mean = s * (1.0f / DM);
  float s2 = 0.0f;
  #pragma unroll
  for (int i = 0; i < 4; ++i) {
    v[i].x -= mean; v[i].y -= mean; v[i].z -= mean; v[i].w -= mean;
    s2 += v[i].x*v[i].x + v[i].y*v[i].y + v[i].z*v[i].z + v[i].w*v[i].w;
  }
  #pragma unroll
  for (int o = 32; o; o >>= 1) s2 += __shfl_xor(s2, o);
  float rs = rsqrtf(s2 * (1.0f / DM) + 1e-5f);
  #pragma unroll
  for (int i = 0; i < 4; ++i) {
    int c = (lane + i * 64) * 4;
    float4 gg = *(const float4*)(g + c);
    float4 bv = *(const float4*)(bb + c);
    float y0 = v[i].x * rs * gg.x + bv.x;
    float y1 = v[i].y * rs * gg.y + bv.y;
    float y2 = v[i].z * rs * gg.z + bv.z;
    float y3 = v[i].w * rs * gg.w + bv.w;
    if (outf32) {
      float4 ov = {y0, y1, y2, y3};
      *(float4*)(of + (size_t)row * DM + c) = ov;
    } else {
      union { bf16 h[4]; uint2 u; } t;
      t.h[0] = __float2bfloat16(y0); t.h[1] = __float2bfloat16(y1);
      t.h[2] = __float2bfloat16(y2); t.h[3] = __float2bfloat16(y3);
      *(uint2*)(ob + (size_t)row * DM + c) = t.u;
    }
  }
}

template<int OUTF32>
__global__ __launch_bounds__(256) void ln_kernel(const float* __restrict__ x,
                                                 const float* __restrict__ g,
                                                 const float* __restrict__ bb,
                                                 bf16* __restrict__ ob,
                                                 float* __restrict__ of) {
  int wv = threadIdx.x >> 6, lane = threadIdx.x & 63;
  int row = blockIdx.x * 4 + wv;
  const float4* xr = (const float4*)(x + (size_t)row * DM);
  float4 v[4];
  #pragma unroll
  for (int i = 0; i < 4; ++i) v[i] = xr[lane + i * 64];
  ln_wave(v, g, bb, row, lane, ob, of, OUTF32);
}

// x += p + bias (single bf16 proj partial), write x back, then LN
template<int OUTF32>
__global__ __launch_bounds__(256) void ln_fused1(float* __restrict__ x,
                                                 const bf16* __restrict__ p,
                                                 const float* __restrict__ bias,
                                                 const float* __restrict__ g,
                                                 const float* __restrict__ bb,
                                                 bf16* __restrict__ ob,
                                                 float* __restrict__ of) {
  int wv = threadIdx.x >> 6, lane = threadIdx.x & 63;
  int row = blockIdx.x * 4 + wv;
  size_t rb = (size_t)row * DM;
  float4 v[4];
  #pragma unroll
  for (int i = 0; i < 4; ++i) {
    int c = (lane + i * 64) * 4;
    float4 xv = *(const float4*)(x + rb + c);
    float4 a0 = ld_bf16x4(p + rb + c);
    float4 bv = *(const float4*)(bias + c);
    xv.x += a0.x + bv.x;
    xv.y += a0.y + bv.y;
    xv.z += a0.z + bv.z;
    xv.w += a0.w + bv.w;
    *(float4*)(x + rb + c) = xv;
    v[i] = xv;
  }
  ln_wave(v, g, bb, row, lane, ob, of, OUTF32);
}

// x += p0+p1+p2+p3 + bias (bf16 split-K=4 partials), write x back, then LN
template<int OUTF32>
__global__ __launch_bounds__(256) void ln_fused4(float* __restrict__ x,
                                                 const bf16* __restrict__ p,
                                                 const float* __restrict__ bias,
                                                 const float* __restrict__ g,
                                                 const float* __restrict__ bb,
                                                 bf16* __restrict__ ob,
                                                 float* __restrict__ of) {
  int wv = threadIdx.x >> 6, lane = threadIdx.x & 63;
  int row = blockIdx.x * 4 + wv;
  size_t rb = (size_t)row * DM;
  const size_t NM = (size_t)NTOK * DM;
  float4 v[4];
  #pragma unroll
  for (int i = 0; i < 4; ++i) {
    int c = (lane + i * 64) * 4;
    float4 xv = *(const float4*)(x + rb + c);
    float4 a0 = ld_bf16x4(p + rb + c);
    float4 a1 = ld_bf16x4(p + NM + rb + c);
    float4 a2 = ld_bf16x4(p + 2*NM + rb + c);
    float4 a3 = ld_bf16x4(p + 3*NM + rb + c);
    float4 bv = *(const float4*)(bias + c);
    xv.x += a0.x + a1.x + a2.x + a3.x + bv.x;
    xv.y += a0.y + a1.y + a2.y + a3.y + bv.y;
    xv.z += a0.z + a1.z + a2.z + a3.z + bv.z;
    xv.w += a0.w + a1.w + a2.w + a3.w + bv.w;
    *(float4*)(x + rb + c) = xv;
    v[i] = xv;
  }
  ln_wave(v, g, bb, row, lane, ob, of, OUTF32);
}

// ---------------- small GEMM: 128 x 64 tile, 4 waves (proven R5 pipeline) ----
// EPI 0: bf16 out, +bias[col]
// EPI 4: bf16 partial Cb[row,col] = acc  (bias folded into ln_fused1)
template<int EPI>
__global__ __launch_bounds__(256) void gemm_bt(const bf16* __restrict__ A,
                                               const bf16* __restrict__ Bt,
                                               const float* __restrict__ bias,
                                               bf16* __restrict__ Cb,
                                               float* __restrict__ Cf,
                                               int M, int N, int K) {
  constexpr int BN = 64, NFR = 2;
  __shared__ bf16 As[3][128 * 32];
  __shared__ bf16 Bs[3][BN * 32];
  int tid = threadIdx.x;
  int wave = tid >> 6, lane = tid & 63;
  int l4 = lane & 15, lhi = lane >> 4;
  int wr = wave >> 1, wc = wave & 1;
  int nwg = gridDim.x * gridDim.y;
  int bid = blockIdx.y * gridDim.x + blockIdx.x;
  int cpx = nwg >> 3;
  int swz = (bid & 7) * cpx + (bid >> 3);
  int bx = swz % gridDim.x, by = swz / gridDim.x;
  int brow = by * 128, bcol = bx * BN;
  f32x4 acc[4][NFR] = {};
  int srow = lane >> 2;
  int scol = (lane & 3) * 8;
  int T = K >> 5;

  auto stage = [&](int buf, int t) {
    int k0 = t * 32;
    #pragma unroll
    for (int i = 0; i < 2; ++i) {
      int rb = i * 64 + wave * 16;
      gl_lds16(A + (size_t)(brow + rb + srow) * K + k0 + scol, &As[buf][rb * 32]);
    }
    int rb = wave * 16;
    gl_lds16(Bt + (size_t)(bcol + rb + srow) * K + k0 + scol, &Bs[buf][rb * 32]);
  };
  auto compute = [&](int buf) {
    bf16x8 af[4], bfv[NFR];
    #pragma unroll
    for (int m = 0; m < 4; ++m)
      af[m] = *(const bf16x8*)&As[buf][(wr * 64 + m * 16 + l4) * 32 + lhi * 8];
    #pragma unroll
    for (int n = 0; n < NFR; ++n)
      bfv[n] = *(const bf16x8*)&Bs[buf][(wc * 32 + n * 16 + l4) * 32 + lhi * 8];
    #pragma unroll
    for (int m = 0; m < 4; ++m)
      #pragma unroll
      for (int n = 0; n < NFR; ++n)
        acc[m][n] = __builtin_amdgcn_mfma_f32_16x16x32_bf16(af[m], bfv[n], acc[m][n], 0, 0, 0);
  };

  stage(0, 0);
  stage(1, 1);
  for (int t = 0; t < T; ++t) {
    if (t < T - 1) asm volatile("s_waitcnt vmcnt(3)" ::: "memory");
    else           asm volatile("s_waitcnt vmcnt(0)" ::: "memory");
    __builtin_amdgcn_s_barrier();
    asm volatile("" ::: "memory");
    if (t + 2 < T) stage((t + 2) % 3, t + 2);
    compute(t % 3);
  }

  #pragma unroll
  for (int m = 0; m < 4; ++m) {
    int row0 = brow + wr * 64 + m * 16 + lhi * 4;
    #pragma unroll
    for (int n = 0; n < NFR; ++n) {
      int col = bcol + wc * 32 + n * 16 + l4;
      #pragma unroll
      for (int r = 0; r < 4; ++r) {
        int row = row0 + r;
        float v = acc[m][n][r];
        if (EPI == 0) {
          v += bias[col];
          Cb[(size_t)row * N + col] = __float2bfloat16(v);
        } else {
          Cb[(size_t)row * N + col] = __float2bfloat16(v);
        }
      }
    }
  }
}

// ---------------- 8-phase 256x256 GEMM body (pipelined subtile reads) --------
// EPI 0: bf16 +bias[col]; 1: +relu; 4: bf16 split-K partial; 5/6: enc remaps;
// EPI 7: fused QKV — V third (bcol>=2048) written TRANSPOSED to vtbuf (via Cf).
template<int EPI>
__device__ __forceinline__ void gemm8x_body(bf16 (*S)[8192],
                                            const bf16* __restrict__ A,
                                            const bf16* __restrict__ Bt,
                                            const float* __restrict__ bias,
                                            bf16* __restrict__ Cb,
                                            float* __restrict__ Cf,
                                            int M, int N, int K,
                                            int bx, int by, int kz) {
  int tid = threadIdx.x;
  int wave = tid >> 6, lane = tid & 63;
  int l4 = lane & 15, lhi = lane >> 4;
  int wr = wave >> 2, wc = wave & 3;
  int brow = by * 256, bcol = bx * 256;
  f32x4 acc[8][4] = {};

  int kbase = 0, Keff = K;
  if (EPI == 4) { Keff = K >> 2; kbase = kz * Keff; }
  int T = Keff >> 6;   // K-tiles of 64

  int srcRow = tid >> 3;
  int srcKb  = ((tid & 7) << 4) ^ (((tid >> 5) & 1) << 5) ^ (((tid >> 4) & 1) << 6);
  int swzr   = (((l4 >> 2) & 1) << 4) ^ (((l4 >> 1) & 1) << 5);

  auto stageA = [&](int d, int half, int kt) {
    #pragma unroll
    for (int j = 0; j < 2; ++j) {
      int r = brow + half * 128 + j * 64 + srcRow;
      if (EPI == 6) r = ((r >> 10) << 12) + 2048 + (r & 1023);
      const char* src = (const char*)(A + (size_t)r * K + kbase + kt * 64) + srcKb;
      gl_lds16(src, (char*)&S[d * 2 + half][0] + j * 8192 + wave * 1024);
    }
  };
  auto stageB = [&](int d, int half, int kt) {
    #pragma unroll
    for (int j = 0; j < 2; ++j) {
      int r = bcol + half * 128 + j * 64 + srcRow;
      if (EPI == 5) r = ((r >> 10) << 12) + 1024 + (r & 1023);
      const char* src = (const char*)(Bt + (size_t)r * K + kbase + kt * 64) + srcKb;
      gl_lds16(src, (char*)&S[4 + d * 2 + half][0] + j * 8192 + wave * 1024);
    }
  };

  stageA(0, 0, 0); stageA(0, 1, 0); stageB(0, 0, 0); stageB(0, 1, 0);

  for (int i = 0; i < T; ++i) {
    int d = i & 1, od = d ^ 1;
    asm volatile("s_waitcnt vmcnt(0)" ::: "memory");
    __builtin_amdgcn_s_barrier();
    asm volatile("" ::: "memory");
    const bf16* As_ = &S[d * 2 + wr][0];
    const bf16* Bs_ = &S[4 + d * 2 + (wc >> 1)][0];
    int rB = (wc & 1) * 64;
    bool st = (i + 1) < T;

    bf16x8 bfv[4][2];
    #pragma unroll
    for (int n = 0; n < 4; ++n) {
      int r = rB + n * 16 + l4;
      #pragma unroll
      for (int ks = 0; ks < 2; ++ks)
        bfv[n][ks] = *(const bf16x8*)&Bs_[r * 64 + ((ks * 32 + lhi * 8) ^ swzr)];
    }
    bf16x8 afA[2][2], afB[2][2];
    #pragma unroll
    for (int mm = 0; mm < 2; ++mm) {
      int r = mm * 16 + l4;
      #pragma unroll
      for (int ks = 0; ks < 2; ++ks)
        afA[mm][ks] = *(const bf16x8*)&As_[r * 64 + ((ks * 32 + lhi * 8) ^ swzr)];
    }
    if (st) { stageA(od, 0, i + 1); stageA(od, 1, i + 1); }

    // q0
    #pragma unroll
    for (int mm = 0; mm < 2; ++mm) {
      int r = (2 + mm) * 16 + l4;
      #pragma unroll
      for (int ks = 0; ks < 2; ++ks)
        afB[mm][ks] = *(const bf16x8*)&As_[r * 64 + ((ks * 32 + lhi * 8) ^ swzr)];
    }
    if (st) { stageB(od, 0, i + 1); stageB(od, 1, i + 1); }
    __builtin_amdgcn_s_setprio(1);
    #pragma unroll
    for (int mm = 0; mm < 2; ++mm)
      #pragma unroll
      for (int ks = 0; ks < 2; ++ks)
        #pragma unroll
        for (int n = 0; n < 4; ++n)
          acc[mm][n] = __builtin_amdgcn_mfma_f32_16x16x32_bf16(afA[mm][ks], bfv[n][ks], acc[mm][n], 0, 0, 0);
    __builtin_amdgcn_s_setprio(0);

    // q1
    #pragma unroll
    for (int mm = 0; mm < 2; ++mm) {
      int r = (4 + mm) * 16 + l4;
      #pragma unroll
      for (int ks = 0; ks < 2; ++ks)
        afA[mm][ks] = *(const bf16x8*)&As_[r * 64 + ((ks * 32 + lhi * 8) ^ swzr)];
    }
    __builtin_amdgcn_s_setprio(1);
    #pragma unroll
    for (int mm = 0; mm < 2; ++mm)
      #pragma unroll
      for (int ks = 0; ks < 2; ++ks)
        #pragma unroll
        for (int n = 0; n < 4; ++n)
          acc[2 + mm][n] = __builtin_amdgcn_mfma_f32_16x16x32_bf16(afB[mm][ks], bfv[n][ks], acc[2 + mm][n], 0, 0, 0);
    __builtin_amdgcn_s_setprio(0);

    // q2
    #pragma unroll
    for (int mm = 0; mm < 2; ++mm) {
      int r = (6 + mm) * 16 + l4;
      #pragma unroll
      for (int ks = 0; ks < 2; ++ks)
        afB[mm][ks] = *(const bf16x8*)&As_[r * 64 + ((ks * 32 + lhi * 8) ^ swzr)];
    }
    __builtin_amdgcn_s_setprio(1);
    #pragma unroll
    for (int mm = 0; mm < 2; ++mm)
      #pragma unroll
      for (int ks = 0; ks < 2; ++ks)
        #pragma unroll
        for (int n = 0; n < 4; ++n)
          acc[4 + mm][n] = __builtin_amdgcn_mfma_f32_16x16x32_bf16(afA[mm][ks], bfv[n][ks], acc[4 + mm][n], 0, 0, 0);
    __builtin_amdgcn_s_setprio(0);

    // q3
    __builtin_amdgcn_s_setprio(1);
    #pragma unroll
    for (int mm = 0; mm < 2; ++mm)
      #pragma unroll
      for (int ks = 0; ks < 2; ++ks)
        #pragma unroll
        for (int n = 0; n < 4; ++n)
          acc[6 + mm][n] = __builtin_amdgcn_mfma_f32_16x16x32_bf16(afB[mm][ks], bfv[n][ks], acc[6 + mm][n], 0, 0, 0);
    __builtin_amdgcn_s_setprio(0);
    asm volatile("" ::: "memory");
  }

  if (EPI == 7) {
    if (bcol >= 2048) {
      // V third: write transposed to vtbuf (passed via Cf), bias added.
      bf16* vt = (bf16*)Cf;
      #pragma unroll
      for (int m = 0; m < 8; ++m) {
        int row0 = brow + wr * 128 + m * 16 + lhi * 4;
        #pragma unroll
        for (int n = 0; n < 4; ++n) {
          int col = bcol + wc * 64 + n * 16 + l4;
          float bv = bias[col];
          union { bf16 h[4]; uint2 u; } t;
          #pragma unroll
          for (int r = 0; r < 4; ++r)
            t.h[r] = __float2bfloat16(acc[m][n][r] + bv);
          *(uint2*)(vt + (size_t)(col - 2048) * NTOK + row0) = t.u;
        }
      }
    } else {
      #pragma unroll
      for (int m = 0; m < 8; ++m) {
        int row0 = brow + wr * 128 + m * 16 + lhi * 4;
        #pragma unroll
        for (int n = 0; n < 4; ++n) {
          int col = bcol + wc * 64 + n * 16 + l4;
          float bv = bias[col];
          #pragma unroll
          for (int r = 0; r < 4; ++r)
            Cb[(size_t)(row0 + r) * N + col] = __float2bfloat16(acc[m][n][r] + bv);
        }
      }
    }
    return;
  }

  #pragma unroll
  for (int m = 0; m < 8; ++m) {
    int row0 = brow + wr * 128 + m * 16 + lhi * 4;
    #pragma unroll
    for (int n = 0; n < 4; ++n) {
      int col = bcol + wc * 64 + n * 16 + l4;
      #pragma unroll
      for (int r = 0; r < 4; ++r) {
        int row = row0 + r;
        float v = acc[m][n][r];
        if (EPI == 0) {
          v += bias[col];
          Cb[(size_t)row * N + col] = __float2bfloat16(v);
        } else if (EPI == 1) {
          v += bias[col];
          v = fmaxf(v, 0.0f);
          Cb[(size_t)row * N + col] = __float2bfloat16(v);
        } else if (EPI == 4) {
          ((bf16*)Cf)[(size_t)kz * ((size_t)M * N) + (size_t)row * N + col] = __float2bfloat16(v);
        } else if (EPI == 5) {
          v += bias[((col >> 10) << 12) + 1024 + (col & 1023)];
          Cb[(size_t)row * N + col] = __float2bfloat16(v);
        } else {
          v += bias[((row >> 10) << 12) + 2048 + (row & 1023)];
          Cb[(size_t)row * N + col] = __float2bfloat16(v);
        }
      }
    }
  }
}

template<int EPI>
__global__ __launch_bounds__(512, 2) void gemm8x(const bf16* __restrict__ A,
                                                 const bf16* __restrict__ Bt,
                                                 const float* __restrict__ bias,
                                                 bf16* __restrict__ Cb,
                                                 float* __restrict__ Cf,
                                                 int M, int N, int K) {
  __shared__ bf16 S[8][8192];
  int nwg = gridDim.x * gridDim.y;
  int bid = blockIdx.y * gridDim.x + blockIdx.x;
  int cpx = nwg >> 3;
  int swz = (bid & 7) * cpx + (bid >> 3);
  int bx = swz % gridDim.x, by = swz / gridDim.x;
  gemm8x_body<EPI>(S, A, Bt, bias, Cb, Cf, M, N, K, bx, by, blockIdx.z);
}

// merged hoisted encoder K / V^T projections: 768 blocks = 3 exact rounds
__global__ __launch_bounds__(512, 2) void gemm8x_dual(const bf16* __restrict__ encb,
                                                      const bf16* __restrict__ wca,
                                                      const float* __restrict__ cab,
                                                      bf16* __restrict__ keall,
                                                      bf16* __restrict__ vteall) {
  __shared__ bf16 S[8][8192];
  int bid = blockIdx.x;
  if (bid < 384) {                               // K_enc: grid 24 x 16
    int swz = (bid & 7) * 48 + (bid >> 3);
    int bx = swz % 24, by = swz / 24;
    gemm8x_body<5>(S, encb, wca, cab, keall, nullptr, NTOK, NL*DM, DM, bx, by, 0);
  } else {                                       // V_enc^T: grid 16 x 24
    int b2 = bid - 384;
    int swz = (b2 & 7) * 48 + (b2 >> 3);
    int bx = swz % 16, by = swz / 16;
    gemm8x_body<6>(S, wca, encb, cab, vteall, nullptr, NL*DM, NTOK, DM, bx, by, 0);
  }
}

// ---------------- fused attention (LDS-staged 64-key tiles + XCD swizzle) ----
template<int CAUSAL>
__global__ __launch_bounds__(256, 2) void attn_kernel(const bf16* __restrict__ qg,
                                                      const bf16* __restrict__ kg,
                                                      const bf16* __restrict__ vtg,
                                                      bf16* __restrict__ og,
                                                      int qs, int ks) {
  __shared__ bf16 P[4][16][520];   // 66,560 B
  __shared__ bf16 KV[4096];        // 8 KB tile: [64 rows][128 B]
  int nwg = gridDim.x * gridDim.y;           // 1024
  int lin = blockIdx.y * gridDim.x + blockIdx.x;
  int swzb = (lin & 7) * (nwg >> 3) + (lin >> 3);
  int qblk = swzb & 7;                        // gridDim.x == 8
  int bh = swzb >> 3;
  int b = bh >> 4, h = bh & 15;
  int wave = threadIdx.x >> 6, lane = threadIdx.x & 63;
  int l4 = lane & 15, lhi = lane >> 4;
  int qbase = qblk * 64 + wave * 16;
  const int qmax = CAUSAL ? (qbase + 15) : 0x7fffffff;    // wave-uniform
  const int tmaxb = CAUSAL ? qblk : 7;                     // block-uniform

  int srow8 = lane >> 3;
  int sbyte = ((lane & 7) * 16) ^ (srow8 << 4);            // pre-swizzled source byte
  int rdswz = (l4 & 7) << 4;                               // read-side XOR

  bf16x8 qa[2];
  {
    size_t qrow = (size_t)(b * SEQL + qbase + l4);
    #pragma unroll
    for (int kk = 0; kk < 2; ++kk)
      qa[kk] = *(const bf16x8*)&qg[qrow * qs + h * HD + kk * 32 + lhi * 8];
  }

  // ---- QK^T over 8 staged 64-key tiles ----
  f32x4 acc[32] = {};
  #pragma unroll
  for (int t = 0; t < 8; ++t) {
    if (t <= tmaxb) {
      #pragma unroll
      for (int j = 0; j < 2; ++j) {
        int row = (wave * 2 + j) * 8 + srow8;
        const char* src = (const char*)(kg + (size_t)(b * SEQL + t * 64 + row) * ks + h * HD) + sbyte;
        gl_lds16(src, (char*)&KV[0] + (wave * 2 + j) * 1024);
      }
      asm volatile("s_waitcnt vmcnt(0)" ::: "memory");
      __builtin_amdgcn_s_barrier();
      asm volatile("" ::: "memory");
      #pragma unroll
      for (int n = 0; n < 4; ++n) {
        int nk = t * 4 + n;
        if (!CAUSAL || nk * 16 <= qmax) {
          #pragma unroll
          for (int kk = 0; kk < 2; ++kk) {
            bf16x8 kf = *(const bf16x8*)((const char*)&KV[0] + (n * 16 + l4) * 128 + ((kk * 64 + lhi * 16) ^ rdswz));
            acc[nk] = __builtin_amdgcn_mfma_f32_16x16x32_bf16(qa[kk], kf, acc[nk], 0, 0, 0);
          }
        }
      }
      __builtin_amdgcn_s_barrier();
      asm volatile("" ::: "memory");
    }
  }

  // ---- softmax ----
  int qloc = qbase + lhi * 4;
  #pragma unroll
  for (int r = 0; r < 4; ++r) {
    float mx = -3.0e38f;
    #pragma unroll
    for (int n = 0; n < 32; ++n) {
      float sv = acc[n][r] * 0.125f;
      if (CAUSAL && (n * 16 + l4 > qloc + r)) sv = -3.0e38f;
      acc[n][r] = sv;
      mx = fmaxf(mx, sv);
    }
    #pragma unroll
    for (int o = 1; o < 16; o <<= 1) mx = fmaxf(mx, __shfl_xor(mx, o));
    float sum = 0.0f;
    #pragma unroll
    for (int n = 0; n < 32; ++n) {
      float p;
      if (CAUSAL && n * 16 > qmax) p = 0.0f;
      else p = __expf(acc[n][r] - mx);
      acc[n][r] = p;
      sum += p;
    }
    #pragma unroll
    for (int o = 1; o < 16; o <<= 1) sum += __shfl_xor(sum, o);
    float rcp = 1.0f / sum;
    #pragma unroll
    for (int n = 0; n < 32; ++n)
      P[wave][lhi * 4 + r][n * 16 + l4] = __float2bfloat16(acc[n][r] * rcp);
  }
  __syncthreads();

  // ---- PV over 8 staged 64-key V^T tiles (reuse KV buffer) ----
  f32x4 oacc[4] = {};
  #pragma unroll
  for (int t = 0; t < 8; ++t) {
    if (t <= tmaxb) {
      #pragma unroll
      for (int j = 0; j < 2; ++j) {
        int row = (wave * 2 + j) * 8 + srow8;
        const char* src = (const char*)(vtg + (size_t)(h * HD + row) * NTOK + b * SEQL + t * 64) + sbyte;
        gl_lds16(src, (char*)&KV[0] + (wave * 2 + j) * 1024);
      }
      asm volatile("s_waitcnt vmcnt(0)" ::: "memory");
      __builtin_amdgcn_s_barrier();
      asm volatile("" ::: "memory");
      #pragma unroll
      for (int ksl = 0; ksl < 2; ++ksl) {
        int kslot = t * 2 + ksl;
        if (!CAUSAL || kslot * 32 <= qmax) {
          bf16x8 pa = *(const bf16x8*)&P[wave][l4][kslot * 32 + lhi * 8];
          #pragma unroll
          for (int nn = 0; nn < 4; ++nn) {
            bf16x8 vf = *(const bf16x8*)((const char*)&KV[0] + (nn * 16 + l4) * 128 + ((ksl * 64 + lhi * 16) ^ rdswz));
            oacc[nn] = __builtin_amdgcn_mfma_f32_16x16x32_bf16(pa, vf, oacc[nn], 0, 0, 0);
          }
        }
      }
      __builtin_amdgcn_s_barrier();
      asm volatile("" ::: "memory");
    }
  }

  size_t orow = (size_t)(b * SEQL + qbase + lhi * 4);
  #pragma unroll
  for (int n = 0; n < 4; ++n)
    #pragma unroll
    for (int r = 0; r < 4; ++r)
      og[(orow + r) * DM + h * HD + n * 16 + l4] = __float2bfloat16(oacc[n][r]);
}

// ---------------- host ----------------
extern "C" void kernel_launch(void* const* d_in, const int* in_sizes, int n_in,
                              void* d_out, int out_size, void* d_ws, size_t ws_size,
                              hipStream_t stream) {
  (void)in_sizes; (void)n_in; (void)out_size;
  const float* enc   = (const float*)d_in[0];
  const int*   toks  = (const int*)  d_in[1];
  const float* table = (const float*)d_in[4];
  const float* sa_w  = (const float*)d_in[5];
  const float* sa_b  = (const float*)d_in[6];
  const float* ca_w  = (const float*)d_in[7];
  const float* ca_b  = (const float*)d_in[8];
  const float* f1w   = (const float*)d_in[9];
  const float* f1b   = (const float*)d_in[10];
  const float* f2w   = (const float*)d_in[11];
  const float* f2b   = (const float*)d_in[12];
  const float* lng   = (const float*)d_in[13];
  const float* lnbp  = (const float*)d_in[14];
  const float* fg    = (const float*)d_in[15];
  const float* fbp   = (const float*)d_in[16];
  float* outp = (float*)d_out;

  char* base = (char*)d_ws;
  size_t off = 0;
  auto alloc = [&](size_t nbytes) -> char* {
    char* p = base + off;
    off += (nbytes + 255) & ~(size_t)255;
    return p;
  };
  const size_t DDb = (size_t)DM * DM;
  bf16* wt_sa   = (bf16*)alloc((size_t)NL * 4 * DDb * 2);
  bf16* wt_ca   = (bf16*)alloc((size_t)NL * 4 * DDb * 2);
  bf16* wt_f1   = (bf16*)alloc((size_t)NL * FF * DM * 2);
  bf16* wt_f2   = (bf16*)alloc((size_t)NL * FF * DM * 2);
  bf16* encb    = (bf16*)alloc((size_t)NTOK * DM * 2);
  bf16* keall   = (bf16*)alloc((size_t)NTOK * NL * DM * 2);   // [4096][6144]
  bf16* vteall  = (bf16*)alloc((size_t)NL * DM * NTOK * 2);   // [6144][4096]
  bf16* hbuf    = (bf16*)alloc((size_t)NTOK * DM * 2);
  bf16* qkvbuf  = (bf16*)alloc((size_t)NTOK * 3 * DM * 2);    // fused Q|K|V (stride 3072)
  bf16* vtbuf   = (bf16*)alloc((size_t)NTOK * DM * 2);
  bf16* aobuf   = (bf16*)alloc((size_t)NTOK * DM * 2);
  bf16* h1buf   = (bf16*)alloc((size_t)NTOK * FF * 2);
  float* xbuf   = (float*)alloc((size_t)NTOK * DM * 4);
  bf16* pbuf4   = (bf16*)alloc((size_t)4 * NTOK * DM * 2);    // bf16 split-K / proj partials
  if (off > ws_size) return;

  transpose_cvt<<<dim3(DM/64, DM/64, NL*4), 256, 0, stream>>>(sa_w, wt_sa, DM, DM);
  transpose_cvt<<<dim3(DM/64, DM/64, NL*4), 256, 0, stream>>>(ca_w, wt_ca, DM, DM);
  transpose_cvt<<<dim3(FF/64, DM/64, NL),   256, 0, stream>>>(f1w, wt_f1, DM, FF);
  transpose_cvt<<<dim3(DM/64, FF/64, NL),   256, 0, stream>>>(f2w, wt_f2, FF, DM);
  cvt_bf16<<<(NTOK * DM / 4) / 256, 256, 0, stream>>>(enc, encb);
  embed_pe<<<NTOK, 256, 0, stream>>>(toks, table, xbuf);

  // merged hoisted all-layer encoder K / V^T projections (768 blocks = 3 rounds)
  gemm8x_dual<<<768, 512, 0, stream>>>(encb, wt_ca, ca_b, keall, vteall);

  // layer-0 pre-norm (later ones fused into proj / FFN2 reduces)
  ln_kernel<0><<<NTOK/4, 256, 0, stream>>>(xbuf, lng + 0*DM, lnbp + 0*DM, hbuf, nullptr);

  for (int l = 0; l < NL; ++l) {
    const bf16* wsa = wt_sa + (size_t)l * 4 * DDb;
    const bf16* wca = wt_ca + (size_t)l * 4 * DDb;
    const float* bsa = sa_b + (size_t)l * 4 * DM;
    const float* bca = ca_b + (size_t)l * 4 * DM;
    // ---- self-attention: fused QKV (N=3072) with V transposed in-epilogue ----
    gemm8x<7><<<dim3(3*DM/256, NTOK/256), 512, 0, stream>>>(hbuf, wsa, bsa, qkvbuf, (float*)vtbuf, NTOK, 3*DM, DM);
    attn_kernel<1><<<dim3(SEQL/64, NB_*NH), 256, 0, stream>>>(qkvbuf, qkvbuf + DM, vtbuf, aobuf, 3*DM, 3*DM);
    gemm_bt<4><<<dim3(DM/64, NTOK/128), 256, 0, stream>>>(aobuf, wsa + 3*DDb, nullptr, pbuf4, nullptr, NTOK, DM, DM);
    ln_fused1<0><<<NTOK/4, 256, 0, stream>>>(xbuf, pbuf4, bsa + 3*DM,
                                             lng + (l*3+1)*DM, lnbp + (l*3+1)*DM, hbuf, nullptr);
    // ---- cross-attention ----
    gemm_bt<0><<<dim3(DM/64, NTOK/128), 256, 0, stream>>>(hbuf, wca + 0*DDb, bca + 0*DM, qkvbuf, nullptr, NTOK, DM, DM);
    attn_kernel<0><<<dim3(SEQL/64, NB_*NH), 256, 0, stream>>>(qkvbuf, keall + l*DM, vteall + (size_t)l*DM*NTOK, aobuf, DM, NL*DM);
    gemm_bt<4><<<dim3(DM/64, NTOK/128), 256, 0, stream>>>(aobuf, wca + 3*DDb, nullptr, pbuf4, nullptr, NTOK, DM, DM);
    ln_fused1<0><<<NTOK/4, 256, 0, stream>>>(xbuf, pbuf4, bca + 3*DM,
                                             lng + (l*3+2)*DM, lnbp + (l*3+2)*DM, hbuf, nullptr);
    // ---- FFN ----
    gemm8x<1><<<dim3(FF/256, NTOK/256), 512, 0, stream>>>(hbuf, wt_f1 + (size_t)l*FF*DM, f1b + (size_t)l*FF, h1buf, nullptr, NTOK, FF, DM);
    gemm8x<4><<<dim3(DM/256, NTOK/256, 4), 512, 0, stream>>>(h1buf, wt_f2 + (size_t)l*FF*DM, nullptr, nullptr, (float*)pbuf4, NTOK, DM, FF);
    if (l < NL - 1)
      ln_fused4<0><<<NTOK/4, 256, 0, stream>>>(xbuf, pbuf4, f2b + (size_t)l*DM,
                                               lng + ((l+1)*3+0)*DM, lnbp + ((l+1)*3+0)*DM, hbuf, nullptr);
    else
      ln_fused4<1><<<NTOK/4, 256, 0, stream>>>(xbuf, pbuf4, f2b + (size_t)l*DM,
                                               fg, fbp, nullptr, outp);
  }
}